// Round 4
// baseline (466.252 us; speedup 1.0000x reference)
//
#include <hip/hip_runtime.h>

#define NB 32
#define NC 512
#define NH 56
#define NW 56
#define HW 3136       // 56*56
#define CHW 1605632   // 512*3136
#define NT 98         // 3136/32 flat tiles per plane
#define TP 32         // positions per tile

// ---------------- K1: per-(b,c) mean/max of relu(x) -> mask ----------------
__global__ __launch_bounds__(256) void k1_mask(const float* __restrict__ x,
                                               float* __restrict__ mask) {
    const int plane = blockIdx.x;  // b*512 + c
    const float4* px = (const float4*)(x + (size_t)plane * HW);
    float lmax = 0.f;
    double lsum = 0.0;
    for (int i = threadIdx.x; i < HW / 4; i += 256) {
        float4 v = px[i];
        float f0 = fmaxf(v.x, 0.f), f1 = fmaxf(v.y, 0.f);
        float f2 = fmaxf(v.z, 0.f), f3 = fmaxf(v.w, 0.f);
        lmax = fmaxf(lmax, fmaxf(fmaxf(f0, f1), fmaxf(f2, f3)));
        lsum += (double)f0 + (double)f1 + (double)f2 + (double)f3;
    }
    for (int off = 32; off; off >>= 1) {
        lsum += __shfl_xor(lsum, off);
        lmax = fmaxf(lmax, __shfl_xor(lmax, off));
    }
    __shared__ double ssum[4];
    __shared__ float smax[4];
    int wid = threadIdx.x >> 6, lane = threadIdx.x & 63;
    if (lane == 0) { ssum[wid] = lsum; smax[wid] = lmax; }
    __syncthreads();
    if (threadIdx.x == 0) {
        double s = ssum[0] + ssum[1] + ssum[2] + ssum[3];
        float m = fmaxf(fmaxf(smax[0], smax[1]), fmaxf(smax[2], smax[3]));
        float avg = (float)(s / 3136.0);
        mask[plane] = ((m - avg) < 0.5f) ? 0.f : 1.f;
    }
}

// ---------------- K0: zero-init accumulators (ws is 0xAA-poisoned) ----------------
__global__ __launch_bounds__(256) void k0_init(double* __restrict__ pooled64,
                                               int* __restrict__ xmaxI) {
    int i = blockIdx.x * 256 + threadIdx.x;   // 16384 total
    pooled64[i] = 0.0;
    xmaxI[i] = 0;
}

// ------ K2 fused: per (b, 32-pos tile): bb + per-channel x2 partial stats ------
// dynamic LDS layout (70784 B): sums[8][32] f64 | xs[512][32] f32 | maxs[8][32] f32
//                               | bbv[32] f32 | maskl[512] f32
__global__ __launch_bounds__(256) void k2_fused(const float* __restrict__ x,
                                                const float* __restrict__ mask,
                                                float* __restrict__ bb,
                                                double* __restrict__ pooled64,
                                                int* __restrict__ xmaxI) {
    const int blk = blockIdx.x;            // b*98 + t
    const int b = blk / NT, t = blk % NT;
    extern __shared__ char smem[];
    double* sums = (double*)smem;                              // 2048 B
    float*  xs   = (float*)(smem + 2048);                      // 65536 B
    float*  maxs = (float*)(smem + 2048 + 65536);              // 1024 B
    float*  bbv  = (float*)(smem + 2048 + 65536 + 1024);       // 128 B
    float*  maskl= (float*)(smem + 2048 + 65536 + 1024 + 128); // 2048 B
    const int tid = threadIdx.x;
    maskl[tid]       = mask[b * NC + tid];
    maskl[tid + 256] = mask[b * NC + tid + 256];
    __syncthreads();
    const size_t base = (size_t)b * CHW + t * TP;
    // phase A: 512 ch x 32 pos -> LDS (128-B aligned segments), relu+mask applied
    for (int i = tid; i < NC * 8; i += 256) {
        int cl = i >> 3, v4 = (i & 7) * 4;
        float4 v = *(const float4*)(x + base + (size_t)cl * HW + v4);
        float mk = maskl[cl];
        v.x = fmaxf(v.x, 0.f) * mk;
        v.y = fmaxf(v.y, 0.f) * mk;
        v.z = fmaxf(v.z, 0.f) * mk;
        v.w = fmaxf(v.w, 0.f) * mk;
        *(float4*)(&xs[cl * TP + v4]) = v;
    }
    __syncthreads();
    // phase B: channel max/sum per position
    {
        int p = tid & 31, q = tid >> 5;
        float cmax = 0.f;
        double csum = 0.0;
        for (int i = 0; i < NC / 8; i++) {
            float f = xs[(q + 8 * i) * TP + p];
            cmax = fmaxf(cmax, f);
            csum += (double)f;
        }
        sums[q * 32 + p] = csum;
        maxs[q * 32 + p] = cmax;
    }
    __syncthreads();
    if (tid < TP) {
        double s = 0.0;
        float m = 0.f;
        for (int q = 0; q < 8; q++) { s += sums[q * 32 + tid]; m = fmaxf(m, maxs[q * 32 + tid]); }
        double cmean = s * (1.0 / 512.0);
        double d = fabs((double)m - cmean);
        float bv = (float)(1.0 - exp(-d));
        bbv[tid] = bv;
        bb[(size_t)b * HW + t * TP + tid] = bv;
    }
    __syncthreads();
    // phase C: per-channel x2 = xs*bbv stats over this tile (bank-rotated reads)
    for (int cc = 0; cc < 2; cc++) {
        int c = tid + cc * 256;
        const float* row = &xs[c * TP];
        float m = 0.f;
        double s = 0.0;
#pragma unroll
        for (int j = 0; j < TP; j++) {
            int p = (j + tid) & 31;
            float v = row[p] * bbv[p];      // identical fp32 mul as K4
            m = fmaxf(m, v);
            s += (double)v;
        }
        atomicAdd(&pooled64[b * NC + c], s);          // fp64: order noise ~1e-16
        atomicMax(&xmaxI[b * NC + c], __float_as_int(m)); // exact (x2 >= 0)
    }
}

// ---------------- K2f: finalize pooled (fp64 sum -> fp32 mean) ----------------
__global__ __launch_bounds__(256) void k2f_final(const double* __restrict__ pooled64,
                                                 float* __restrict__ pooledF) {
    int i = blockIdx.x * 256 + threadIdx.x;   // 16384 total
    pooledF[i] = (float)(pooled64[i] / 3136.0);
}

// ------------- K3: FC gates (wave-per-output dot products) -> thres -------------
__global__ __launch_bounds__(256) void k3_gates(const float* __restrict__ pooled,
                                                const float* __restrict__ W1,
                                                const float* __restrict__ W3,
                                                const float* __restrict__ xmaxF,
                                                float* __restrict__ thres) {
    int wave = threadIdx.x >> 6, lane = threadIdx.x & 63;
    int task0 = (blockIdx.x * 4 + wave) * 4;
    for (int t = 0; t < 4; t++) {
        int task = task0 + t;                       // b*512 + j
        int b = task >> 9, j = task & 511;
        const float* r1 = W1 + j * 512;
        const float* r3 = W3 + j * 512;
        const float* pr = pooled + b * 512;
        double s1 = 0.0, s3 = 0.0;
        for (int k = lane; k < 512; k += 64) {
            double p = (double)pr[k];
            s1 += p * (double)r1[k];
            s3 += p * (double)r3[k];
        }
        for (int off = 32; off; off >>= 1) {
            s1 += __shfl_xor(s1, off);
            s3 += __shfl_xor(s3, off);
        }
        if (lane == 0) {
            float c1 = (float)(1.0 / (1.0 + exp(-s1)));   // sigmoid
            double r = s3 > 0.0 ? s3 : 0.0;               // relu
            float c3 = (float)((r < 1.0) ? 1.2 : r);
            thres[task] = c1 * c3 * xmaxF[task];          // np's fp32 mul order
        }
    }
}

// ---------------- K4: recompute x2, threshold, write fp32 out ----------------
__global__ __launch_bounds__(256) void k4_out(const float* __restrict__ x,
                                              const float* __restrict__ mask,
                                              const float* __restrict__ bb,
                                              const float* __restrict__ thres,
                                              float* __restrict__ out) {
    const int plane = blockIdx.x;
    const int b = plane >> 9;
    const float4* px = (const float4*)(x + (size_t)plane * HW);
    float4* po = (float4*)(out + (size_t)plane * HW);
    const float4* pbb = (const float4*)(bb + (size_t)b * HW);
    const float th = thres[plane];
    const float mk = mask[plane];
    for (int i = threadIdx.x; i < HW / 4; i += 256) {
        float4 v = px[i];
        float4 bv = pbb[i];
        float x0 = fmaxf(v.x, 0.f) * mk * bv.x;  // identical fp32 chain as K2 phase C
        float x1 = fmaxf(v.y, 0.f) * mk * bv.y;
        float x2 = fmaxf(v.z, 0.f) * mk * bv.z;
        float x3 = fmaxf(v.w, 0.f) * mk * bv.w;
        float4 o;
        o.x = (x0 < th) ? 0.f : x0;
        o.y = (x1 < th) ? 0.f : x1;
        o.z = (x2 < th) ? 0.f : x2;
        o.w = (x3 < th) ? 0.f : x3;
        po[i] = o;
    }
}

extern "C" void kernel_launch(void* const* d_in, const int* in_sizes, int n_in,
                              void* d_out, int out_size, void* d_ws, size_t ws_size,
                              hipStream_t stream) {
    const float* x  = (const float*)d_in[0];
    const float* W1 = (const float*)d_in[1];
    const float* W3 = (const float*)d_in[2];
    float* out = (float*)d_out;
    char* ws = (char*)d_ws;
    // ws layout (bytes), pooled64 first for 8-B alignment; total 794,624 B
    double* pooled64 = (double*)ws;                 // 131072 B
    int*    xmaxI    = (int*)(ws + 131072);         // 65536 B
    float*  mask     = (float*)(ws + 196608);       // 65536 B
    float*  bb       = (float*)(ws + 262144);       // 401408 B
    float*  pooledF  = (float*)(ws + 663552);       // 65536 B
    float*  thres    = (float*)(ws + 729088);       // 65536 B

    // allow 70784 B dynamic LDS for k2_fused (idempotent; same work every call)
    (void)hipFuncSetAttribute((const void*)k2_fused,
                              hipFuncAttributeMaxDynamicSharedMemorySize, 70784);

    hipLaunchKernelGGL(k1_mask,  dim3(NB * NC), dim3(256), 0, stream, x, mask);
    hipLaunchKernelGGL(k0_init,  dim3(64),      dim3(256), 0, stream, pooled64, xmaxI);
    hipLaunchKernelGGL(k2_fused, dim3(NB * NT), dim3(256), 70784, stream,
                       x, mask, bb, pooled64, xmaxI);
    hipLaunchKernelGGL(k2f_final, dim3(64),     dim3(256), 0, stream, pooled64, pooledF);
    hipLaunchKernelGGL(k3_gates, dim3(1024),    dim3(256), 0, stream,
                       pooledF, W1, W3, (const float*)xmaxI, thres);
    hipLaunchKernelGGL(k4_out,   dim3(NB * NC), dim3(256), 0, stream, x, mask, bb, thres, out);
}